// Round 9
// baseline (604.311 us; speedup 1.0000x reference)
//
#include <hip/hip_runtime.h>
#include <hip/hip_bf16.h>
#include <math.h>

#define B_TOTAL 131072
#define NX 64
#define H 512
#define LD 8
#define NT 45          // 1 + 8 + 36
#define NSTEPS 20

#define NTH 512        // 8 waves
#define BM 64          // rows per block
#define ASTR 520       // bf16 elements per activation row (1040B stride: 2-way bank alias only)

// ---- padded-chunk B layout for the 512x512 layers ----
#define BROW 40                       // padded row elems (80 B: lanes 0-7 partition all 32 banks)
#define BSLICE 2560                   // per-wave slice elems per chunk (64 cols * 40)
#define BCH 20480                     // full chunk elems (512 * 40)

// ws layout (bf16 elements)
#define OFF_EW1T 0                    // [2][512][32] flat chunked (enc1, K=64)
#define OFF_EW2P 32768                // [16][512][40] padded (enc2)
#define OFF_DW2P 360448               // [16][512][40] padded (dec2)
#define OFF_DW3T 688128               // [16][64][32] (dec3)
#define OFF_W3HI 720896               // [16][512] flat: bf16 hi of eW3^T (rows 8..15 zero)
#define OFF_W3LO 729088               // [16][512] flat: lo correction
#define OFF_DW1P 737280               // [512][32] hi/lo packed dW1 panel: slots [wh|wl|wh|wl]
#define WS_ALL   753664               // elems; * 2 bytes = 1,507,328
#define ZT_OFF_BYTES ((size_t)WS_ALL * 2)
#define WS_NEW_BYTES (ZT_OFF_BYTES + (size_t)B_TOTAL * LD * 4)

typedef __attribute__((ext_vector_type(8))) short short8;
typedef __attribute__((ext_vector_type(4))) float f32x4;

__device__ __forceinline__ ushort f2bf(float f) {
    union { float f; uint u; } v; v.f = f;
    uint u = v.u;
    u += 0x7fff + ((u >> 16) & 1);          // RNE
    return (ushort)(u >> 16);
}
__device__ __forceinline__ float bf2f(ushort s) {
    union { uint u; float f; } v; v.u = ((uint)s) << 16;
    return v.f;
}
__device__ __forceinline__ float silu_f(float v) {
    return v / (1.0f + __expf(-v));
}

// ---------------- weight prep ----------------
__global__ void prep_weights(const float* __restrict__ eW1, const float* __restrict__ eW2,
                             const float* __restrict__ dW2, const float* __restrict__ dW3,
                             const float* __restrict__ eW3, const float* __restrict__ dW1,
                             short* __restrict__ ws) {
    const int id = blockIdx.x * 256 + threadIdx.x;
    if (id < OFF_EW2P) {                               // eW1c [2][512][32]
        const int kc = id >> 14, n = (id >> 5) & 511, kk = id & 31;
        ws[id] = (short)f2bf(eW1[(kc * 32 + kk) * H + n]);
    } else if (id < OFF_DW2P) {                        // eW2P [16][512][40] padded
        const int j = id - OFF_EW2P;
        const int kc = j / BCH, rm = j % BCH, n = rm / BROW, s = rm % BROW;
        ws[id] = (s < 32) ? (short)f2bf(eW2[(kc * 32 + s) * H + n]) : (short)0;
    } else if (id < OFF_DW3T) {                        // dW2P [16][512][40] padded
        const int j = id - OFF_DW2P;
        const int kc = j / BCH, rm = j % BCH, n = rm / BROW, s = rm % BROW;
        ws[id] = (s < 32) ? (short)f2bf(dW2[(kc * 32 + s) * H + n]) : (short)0;
    } else if (id < OFF_W3HI) {                        // dW3c [16][64][32]
        const int j = id - OFF_DW3T;
        const int kc = j >> 11, n = (j >> 5) & 63, kk = j & 31;
        ws[id] = (short)f2bf(dW3[(kc * 32 + kk) * NX + n]);
    } else if (id < OFF_W3LO) {                        // eW3T hi [16][512] flat
        const int j = id - OFF_W3HI, n = j >> 9, k = j & 511;
        const float v = (n < LD) ? eW3[k * LD + n] : 0.f;
        ws[id] = (short)f2bf(v);
    } else if (id < OFF_DW1P) {                        // eW3T lo
        const int j = id - OFF_W3LO, n = j >> 9, k = j & 511;
        const float v = (n < LD) ? eW3[k * LD + n] : 0.f;
        const float hi = bf2f(f2bf(v));
        ws[id] = (short)f2bf(v - hi);
    } else if (id < WS_ALL) {                          // dW1 packed [512][32]: k-slots [wh|wl|wh|wl]
        const int j = id - OFF_DW1P;
        const int n = j >> 5, s = j & 31;
        const int k = s & 7;
        const float v = dW1[k * H + n];
        const ushort hi = f2bf(v);
        ws[id] = (((s >> 3) & 1) == 0) ? (short)hi : (short)f2bf(v - bf2f(hi));
    }
}

// ---------------- async global->LDS helper (size must be literal 16) ----------------
__device__ __forceinline__ void load_lds16(const void* g, void* l) {
    __builtin_amdgcn_global_load_lds(
        (const __attribute__((address_space(1))) void*)g,
        (__attribute__((address_space(3))) void*)l, 16, 0, 0);
}

// per-wave 5-KB slice stage: 5 x 1KB linear copies (lds dest = wave-uniform base + lane*16)
__device__ __forceinline__ void stage_slice(const short* __restrict__ gsrc, short* ldst, int lane) {
#pragma unroll
    for (int j = 0; j < 5; ++j) {
        const int off = j * 1024 + lane * 16;   // bytes
        load_lds16((const char*)gsrc + off, (char*)ldst + off);
    }
}

// ---------------- 512x512 GEMM: per-wave async-pipelined B, ZERO intra-loop barriers ----------------
// Wave w owns all 64 rows x cols [w*64,w*64+64). Stage chunk kc+1 while computing kc;
// counted s_waitcnt vmcnt(5) (T4): stage(kc)'s 5 loads are the only ops older than the newest 5.
__device__ __forceinline__ void gemm_lds512(const short (*act)[ASTR], const short* __restrict__ WP,
                                            short* bwave, f32x4 (&acc)[4][4],
                                            int w, int lane, int lm, int q) {
    const short* gbase = WP + w * BSLICE;
    stage_slice(gbase, bwave, lane);                 // chunk 0 -> buf 0
#pragma unroll 1
    for (int kc = 0; kc < 16; ++kc) {
        if (kc + 1 < 16) {
            stage_slice(gbase + (kc + 1) * BCH, bwave + ((kc + 1) & 1) * BSLICE, lane);
            asm volatile("s_waitcnt vmcnt(5)" ::: "memory");
        } else {
            asm volatile("s_waitcnt vmcnt(0)" ::: "memory");
        }
        const short* bb = bwave + (kc & 1) * BSLICE;
        short8 b[4];
#pragma unroll
        for (int tt = 0; tt < 4; ++tt)
            b[tt] = *(const short8*)(bb + (tt * 16 + lm) * BROW + q * 8);
        const int k0 = kc * 32 + q * 8;
#pragma unroll
        for (int mt = 0; mt < 4; ++mt) {
            short8 a = *(const short8*)&act[mt * 16 + lm][k0];
#pragma unroll
            for (int tt = 0; tt < 4; ++tt)
                acc[mt][tt] = __builtin_amdgcn_mfma_f32_16x16x32_bf16(a, b[tt], acc[mt][tt], 0, 0, 0);
        }
    }
}

// ---------------- enc1 direct GEMM (K=64, flat chunked B from L2) ----------------
__device__ __forceinline__ void gemm_direct64(const short (*act)[ASTR], const short* __restrict__ WTc,
                                              f32x4 (&acc)[4][4], int w, int lm, int q) {
    const short* bp = WTc + (w * 64 + lm) * 32 + q * 8;
#pragma unroll 1
    for (int kc = 0; kc < 2; ++kc) {
        short8 b[4];
        const short* p = bp + kc * (H * 32);
#pragma unroll
        for (int tt = 0; tt < 4; ++tt) b[tt] = *(const short8*)(p + tt * 512);
        const int k0 = kc * 32 + q * 8;
#pragma unroll
        for (int mt = 0; mt < 4; ++mt) {
            short8 a = *(const short8*)&act[mt * 16 + lm][k0];
#pragma unroll
            for (int tt = 0; tt < 4; ++tt)
                acc[mt][tt] = __builtin_amdgcn_mfma_f32_16x16x32_bf16(a, b[tt], acc[mt][tt], 0, 0, 0);
        }
    }
}

// ---------------- bias + LayerNorm + SiLU epilogue, 1x8 grid ----------------
__device__ __forceinline__ void ln_epi64(f32x4 (&acc)[4][4],
        const float* __restrict__ bias, const float* __restrict__ g, const float* __restrict__ be,
        short (*act)[ASTR], float (*p1)[8], float (*p2)[8], float (*rstat)[2],
        int w, int lane, int tid) {
    const int lm = lane & 15, q = lane >> 4;
    float cb[4], cg[4], cbe[4];
#pragma unroll
    for (int tt = 0; tt < 4; ++tt) {
        const int c = w * 64 + tt * 16 + lm;
        cb[tt] = bias[c]; cg[tt] = g[c]; cbe[tt] = be[c];
    }
#pragma unroll
    for (int mt = 0; mt < 4; ++mt) {
        float s1[4] = {0.f, 0.f, 0.f, 0.f}, s2[4] = {0.f, 0.f, 0.f, 0.f};
#pragma unroll
        for (int tt = 0; tt < 4; ++tt)
#pragma unroll
            for (int r = 0; r < 4; ++r) {
                float v = acc[mt][tt][r] + cb[tt];
                acc[mt][tt][r] = v;
                s1[r] += v;
                s2[r] += v * v;
            }
#pragma unroll
        for (int m = 1; m < 16; m <<= 1) {
#pragma unroll
            for (int r = 0; r < 4; ++r) {
                s1[r] += __shfl_xor(s1[r], m);
                s2[r] += __shfl_xor(s2[r], m);
            }
        }
        if (lm == 0) {
#pragma unroll
            for (int r = 0; r < 4; ++r) {
                const int row = mt * 16 + q * 4 + r;
                p1[row][w] = s1[r];
                p2[row][w] = s2[r];
            }
        }
    }
    __syncthreads();
    if (tid < BM) {
        float a = 0.f, b2 = 0.f;
#pragma unroll
        for (int j = 0; j < 8; ++j) { a += p1[tid][j]; b2 += p2[tid][j]; }
        const float mean = a * (1.0f / H);
        rstat[tid][0] = mean;
        rstat[tid][1] = rsqrtf(b2 * (1.0f / H) - mean * mean + 1e-5f);
    }
    __syncthreads();
#pragma unroll
    for (int mt = 0; mt < 4; ++mt) {
#pragma unroll
        for (int r = 0; r < 4; ++r) {
            const int row = mt * 16 + q * 4 + r;
            const float mu = rstat[row][0], rs = rstat[row][1];
#pragma unroll
            for (int tt = 0; tt < 4; ++tt) {
                const float v = (acc[mt][tt][r] - mu) * rs * cg[tt] + cbe[tt];
                act[row][w * 64 + tt * 16 + lm] = (short)f2bf(silu_f(v));
            }
        }
    }
    __syncthreads();
}

// ==================== K1: x0 -> encoder -> Euler -> z_t ====================
__global__ __launch_bounds__(NTH, 2) void sindy_enc_kernel(
        const float* __restrict__ x0, const float* __restrict__ logdt,
        const float* __restrict__ eb1, const float* __restrict__ eg1, const float* __restrict__ ebe1,
        const float* __restrict__ eb2, const float* __restrict__ eg2, const float* __restrict__ ebe2,
        const float* __restrict__ eb3, const float* __restrict__ Xi,
        const short* __restrict__ wsb, float* __restrict__ zt) {
    __shared__ __align__(16) short act[BM][ASTR];              // 66,560 B
    __shared__ __align__(16) short bbuf[8 * 2 * BSLICE];       // 81,920 B (per-wave dbuf slices)
    __shared__ float rstat[BM][2];
    __shared__ float dtb[BM];
    __shared__ float xis[NT * LD];
    // epilogue scratch aliases bbuf (time-disjoint with staging)
    float (*p1)[8] = (float(*)[8])bbuf;                        // 2 KB
    float (*p2)[8] = (float(*)[8])(bbuf + 1024);               // 2 KB
    float (*partial)[BM][LD] = (float(*)[BM][LD])bbuf;         // 8 KB (enc3 only)

    const int tid = threadIdx.x;
    const int w = tid >> 6, lane = tid & 63, lm = lane & 15, q = lane >> 4;
    const int row0 = blockIdx.x * BM;
    short* bwave = bbuf + w * 2 * BSLICE;

    if (tid < NT * LD) xis[tid] = Xi[tid];
    if (tid < BM) dtb[tid] = logdt[row0 + tid] * (1.0f / NSTEPS);
    {   // stage x0 tile fp32 -> bf16 LDS (64 rows x 64 cols), coalesced
        const int r = tid >> 3, c8 = (tid & 7) * 8;
        const float* xr = &x0[(row0 + r) * NX + c8];
        const float4 va = *(const float4*)xr;
        const float4 vb = *(const float4*)(xr + 4);
        short8 sv;
        sv[0] = (short)f2bf(va.x); sv[1] = (short)f2bf(va.y);
        sv[2] = (short)f2bf(va.z); sv[3] = (short)f2bf(va.w);
        sv[4] = (short)f2bf(vb.x); sv[5] = (short)f2bf(vb.y);
        sv[6] = (short)f2bf(vb.z); sv[7] = (short)f2bf(vb.w);
        *(short8*)&act[r][c8] = sv;
    }
    __syncthreads();

    // ---- enc1: 64 -> 512 (direct B from L2) ----
    {
        f32x4 acc[4][4];
#pragma unroll
        for (int mt = 0; mt < 4; ++mt)
#pragma unroll
            for (int tt = 0; tt < 4; ++tt) acc[mt][tt] = (f32x4){0.f, 0.f, 0.f, 0.f};
        gemm_direct64(act, wsb + OFF_EW1T, acc, w, lm, q);
        ln_epi64(acc, eb1, eg1, ebe1, act, p1, p2, rstat, w, lane, tid);
    }

    // ---- enc2: 512 -> 512 (async per-wave LDS pipeline, barrier-free K-loop) ----
    {
        f32x4 acc[4][4];
#pragma unroll
        for (int mt = 0; mt < 4; ++mt)
#pragma unroll
            for (int tt = 0; tt < 4; ++tt) acc[mt][tt] = (f32x4){0.f, 0.f, 0.f, 0.f};
        gemm_lds512(act, wsb + OFF_EW2P, bwave, acc, w, lane, lm, q);
        ln_epi64(acc, eb2, eg2, ebe2, act, p1, p2, rstat, w, lane, tid);
    }

    // ---- enc3: 512 -> 8 via MFMA, hi/lo bf16 weight split (~fp32 weight precision) ----
    float z0;
    {
        const short* W3H = wsb + OFF_W3HI;
        const short* W3L = wsb + OFF_W3LO;
        const int kq = w & 3, mh = w >> 2;
        f32x4 a3[2];
        a3[0] = (f32x4){0.f, 0.f, 0.f, 0.f};
        a3[1] = (f32x4){0.f, 0.f, 0.f, 0.f};
#pragma unroll
        for (int kc = 0; kc < 4; ++kc) {
            const int k0 = kq * 128 + kc * 32 + q * 8;
            short8 bh = *(const short8*)&W3H[lm * H + k0];
            short8 bl = *(const short8*)&W3L[lm * H + k0];
#pragma unroll
            for (int i = 0; i < 2; ++i) {
                short8 a = *(const short8*)&act[(mh * 2 + i) * 16 + lm][k0];
                a3[i] = __builtin_amdgcn_mfma_f32_16x16x32_bf16(a, bh, a3[i], 0, 0, 0);
                a3[i] = __builtin_amdgcn_mfma_f32_16x16x32_bf16(a, bl, a3[i], 0, 0, 0);
            }
        }
        if (lm < 8) {
#pragma unroll
            for (int i = 0; i < 2; ++i)
#pragma unroll
                for (int r = 0; r < 4; ++r)
                    partial[kq][(mh * 2 + i) * 16 + q * 4 + r][lm] = a3[i][r];
        }
        __syncthreads();
        {
            const int r = tid >> 3, c = tid & 7;
            const float s = partial[0][r][c] + partial[1][r][c] +
                            partial[2][r][c] + partial[3][r][c];
            z0 = tanhf(s + eb3[c]);
        }
    }

    // ---- SINDy Euler: barrier-free, all coefficients in registers (256-reg budget) ----
    {
        const int r = tid >> 3, c = tid & 7;
        const int lbase = lane & ~7;
        float xr[NT];
#pragma unroll
        for (int t = 0; t < NT; ++t) xr[t] = xis[t * LD + c];
        const float dtv = dtb[r];
        float zc = z0;
        for (int st = 0; st < NSTEPS; ++st) {
            float z[LD];
#pragma unroll
            for (int j = 0; j < LD; ++j) z[j] = __shfl(zc, lbase + j);
            float zd = xr[0];
#pragma unroll
            for (int j = 0; j < LD; ++j) zd += z[j] * xr[1 + j];
            int idx = 1 + LD;
#pragma unroll
            for (int i = 0; i < LD; ++i)
#pragma unroll
                for (int j = i; j < LD; ++j) {
                    zd += z[i] * z[j] * xr[idx];
                    ++idx;
                }
            zc += zd * dtv;
        }
        zt[row0 * LD + tid] = zc;   // coalesced
    }
}

// ==================== K2: z_t -> decoder -> out ====================
__global__ __launch_bounds__(NTH, 2) void sindy_dec_kernel(
        const float* __restrict__ zt,
        const float* __restrict__ db1,
        const float* __restrict__ dg1, const float* __restrict__ dbe1,
        const float* __restrict__ db2, const float* __restrict__ dg2, const float* __restrict__ dbe2,
        const float* __restrict__ db3,
        const short* __restrict__ wsb, float* __restrict__ out) {
    __shared__ __align__(16) short act[BM][ASTR];
    __shared__ __align__(16) short bbuf[8 * 2 * BSLICE];
    __shared__ float rstat[BM][2];
    __shared__ __align__(16) float zbuf[BM][LD];
    float (*p1)[8] = (float(*)[8])bbuf;
    float (*p2)[8] = (float(*)[8])(bbuf + 1024);

    const int tid = threadIdx.x;
    const int w = tid >> 6, lane = tid & 63, lm = lane & 15, q = lane >> 4;
    const int row0 = blockIdx.x * BM;
    short* bwave = bbuf + w * 2 * BSLICE;

    ((float*)zbuf)[tid] = zt[row0 * LD + tid];
    __syncthreads();

    // ---- dec1: 8 -> 512 via MFMA, hi/lo packed K=32 frags (~fp32 precision) ----
    {
        const short* bp = wsb + OFF_DW1P + (w * 64 + lm) * 32 + q * 8;
        short8 b[4];
#pragma unroll
        for (int tt = 0; tt < 4; ++tt) b[tt] = *(const short8*)(bp + tt * 512);
        f32x4 acc[4][4];
#pragma unroll
        for (int mt = 0; mt < 4; ++mt) {
            const int row = mt * 16 + lm;
            const float4 za = *(const float4*)&zbuf[row][0];
            const float4 zb = *(const float4*)&zbuf[row][4];
            float zv[LD] = {za.x, za.y, za.z, za.w, zb.x, zb.y, zb.z, zb.w};
            short8 a;
#pragma unroll
            for (int j = 0; j < LD; ++j) {
                const ushort h = f2bf(zv[j]);
                a[j] = (q < 2) ? (short)h : (short)f2bf(zv[j] - bf2f(h));
            }
#pragma unroll
            for (int tt = 0; tt < 4; ++tt)
                acc[mt][tt] = __builtin_amdgcn_mfma_f32_16x16x32_bf16(
                    a, b[tt], (f32x4){0.f, 0.f, 0.f, 0.f}, 0, 0, 0);
        }
        ln_epi64(acc, db1, dg1, dbe1, act, p1, p2, rstat, w, lane, tid);
    }

    // ---- dec2: 512 -> 512 (async per-wave LDS pipeline, barrier-free K-loop) ----
    {
        f32x4 acc[4][4];
#pragma unroll
        for (int mt = 0; mt < 4; ++mt)
#pragma unroll
            for (int tt = 0; tt < 4; ++tt) acc[mt][tt] = (f32x4){0.f, 0.f, 0.f, 0.f};
        gemm_lds512(act, wsb + OFF_DW2P, bwave, acc, w, lane, lm, q);
        ln_epi64(acc, db2, dg2, dbe2, act, p1, p2, rstat, w, lane, tid);
    }

    // ---- dec3: 512 -> 64 + bias, fp32 out. wave w: nt = w&3, rows (w>>2)*32..+31 ----
    {
        const short* W3c = wsb + OFF_DW3T;
        const int nt = w & 3, mtb = (w >> 2) << 1;
        const short* bp = W3c + (nt * 16 + lm) * 32 + q * 8;
        f32x4 a2[2];
        a2[0] = (f32x4){0.f, 0.f, 0.f, 0.f};
        a2[1] = (f32x4){0.f, 0.f, 0.f, 0.f};
#pragma unroll 1
        for (int kc = 0; kc < 16; ++kc) {
            short8 b = *(const short8*)(bp + kc * 2048);
            const int k0 = kc * 32 + q * 8;
#pragma unroll
            for (int i = 0; i < 2; ++i) {
                short8 a = *(const short8*)&act[(mtb + i) * 16 + lm][k0];
                a2[i] = __builtin_amdgcn_mfma_f32_16x16x32_bf16(a, b, a2[i], 0, 0, 0);
            }
        }
        const int c = nt * 16 + lm;
        const float bb = db3[c];
#pragma unroll
        for (int i = 0; i < 2; ++i)
#pragma unroll
            for (int r = 0; r < 4; ++r) {
                const int row = (mtb + i) * 16 + q * 4 + r;
                out[(row0 + row) * NX + c] = a2[i][r] + bb;
            }
    }
}

// =================== fallback (fp32 kernel, no ws needed) ===================
#define FB_R 16
#define FB_STRIDE 520
#define FB_NT 256

__device__ __forceinline__ void fb_ln_silu(float buf[FB_R][FB_STRIDE],
                                           const float* __restrict__ g,
                                           const float* __restrict__ be, int t) {
    const int r = t >> 4, lane = t & 15;
    float s1 = 0.f, s2 = 0.f;
#pragma unroll
    for (int j = 0; j < H / 16; ++j) {
        float v = buf[r][lane + 16 * j];
        s1 += v; s2 += v * v;
    }
#pragma unroll
    for (int m = 8; m >= 1; m >>= 1) {
        s1 += __shfl_xor(s1, m, 16);
        s2 += __shfl_xor(s2, m, 16);
    }
    const float mean = s1 * (1.0f / H);
    const float var = s2 * (1.0f / H) - mean * mean;
    const float rstd = rsqrtf(var + 1e-5f);
#pragma unroll
    for (int j = 0; j < H / 16; ++j) {
        const int c = lane + 16 * j;
        float v = buf[r][c];
        buf[r][c] = silu_f((v - mean) * rstd * g[c] + be[c]);
    }
}

template <int K>
__device__ __forceinline__ void fb_gemmK(const float in[FB_R][FB_STRIDE], float out[FB_R][FB_STRIDE],
                                         const float* __restrict__ W,
                                         const float* __restrict__ b, int t) {
    const int c0 = t, c1 = t + 256;
    float acc0[FB_R], acc1[FB_R];
#pragma unroll
    for (int r = 0; r < FB_R; ++r) { acc0[r] = 0.f; acc1[r] = 0.f; }
    for (int k = 0; k < K; k += 4) {
        const float w00 = W[(k + 0) * H + c0], w10 = W[(k + 0) * H + c1];
        const float w01 = W[(k + 1) * H + c0], w11 = W[(k + 1) * H + c1];
        const float w02 = W[(k + 2) * H + c0], w12 = W[(k + 2) * H + c1];
        const float w03 = W[(k + 3) * H + c0], w13 = W[(k + 3) * H + c1];
#pragma unroll
        for (int r = 0; r < FB_R; ++r) {
            const float4 h = *(const float4*)&in[r][k];
            acc0[r] += h.x * w00 + h.y * w01 + h.z * w02 + h.w * w03;
            acc1[r] += h.x * w10 + h.y * w11 + h.z * w12 + h.w * w13;
        }
    }
    const float b0 = b[c0], b1 = b[c1];
#pragma unroll
    for (int r = 0; r < FB_R; ++r) {
        out[r][c0] = acc0[r] + b0;
        out[r][c1] = acc1[r] + b1;
    }
}

__global__ __launch_bounds__(FB_NT, 2) void sindy_fallback_kernel(
    const float* __restrict__ x0, const float* __restrict__ logdt,
    const float* __restrict__ eW1, const float* __restrict__ eb1,
    const float* __restrict__ eg1, const float* __restrict__ ebe1,
    const float* __restrict__ eW2, const float* __restrict__ eb2,
    const float* __restrict__ eg2, const float* __restrict__ ebe2,
    const float* __restrict__ eW3, const float* __restrict__ eb3,
    const float* __restrict__ dW1, const float* __restrict__ db1,
    const float* __restrict__ dg1, const float* __restrict__ dbe1,
    const float* __restrict__ dW2, const float* __restrict__ db2,
    const float* __restrict__ dg2, const float* __restrict__ dbe2,
    const float* __restrict__ dW3, const float* __restrict__ db3,
    const float* __restrict__ Xi, float* __restrict__ out) {
    __shared__ float sA[FB_R][FB_STRIDE];
    __shared__ float sB[FB_R][FB_STRIDE];
    __shared__ float zbuf[FB_R][LD];
    __shared__ float dtb[FB_R];
    __shared__ float xis[NT * LD];

    const int t = threadIdx.x;
    const int row0 = blockIdx.x * FB_R;

    for (int i = t; i < NT * LD; i += FB_NT) xis[i] = Xi[i];
    if (t < FB_R) dtb[t] = logdt[row0 + t] * (1.0f / NSTEPS);
    {
        const int r = t >> 4, k4 = (t & 15) * 4;
        *(float4*)&sB[r][k4] = *(const float4*)&x0[(row0 + r) * NX + k4];
    }
    __syncthreads();
    fb_gemmK<NX>(sB, sA, eW1, eb1, t);
    __syncthreads();
    fb_ln_silu(sA, eg1, ebe1, t);
    __syncthreads();
    fb_gemmK<H>(sA, sB, eW2, eb2, t);
    __syncthreads();
    fb_ln_silu(sB, eg2, ebe2, t);
    __syncthreads();
    if (t < FB_R * LD) {
        const int r = t >> 3, c = t & 7;
        float acc = 0.f;
        for (int k = 0; k < H; k += 4) {
            const float4 h = *(const float4*)&sB[r][k];
            acc += h.x * eW3[(k + 0) * LD + c] + h.y * eW3[(k + 1) * LD + c] +
                   h.z * eW3[(k + 2) * LD + c] + h.w * eW3[(k + 3) * LD + c];
        }
        zbuf[r][c] = tanhf(acc + eb3[c]);
    }
    __syncthreads();
    for (int s = 0; s < NSTEPS; ++s) {
        float zn = 0.f;
        const int r = t >> 3, c = t & 7;
        if (t < FB_R * LD) {
            float z[LD];
#pragma unroll
            for (int j = 0; j < LD; ++j) z[j] = zbuf[r][j];
            float zd = xis[c];
#pragma unroll
            for (int j = 0; j < LD; ++j) zd += z[j] * xis[(1 + j) * LD + c];
            int idx = 1 + LD;
#pragma unroll
            for (int i = 0; i < LD; ++i)
#pragma unroll
                for (int j = i; j < LD; ++j) {
                    zd += z[i] * z[j] * xis[idx * LD + c];
                    ++idx;
                }
            zn = z[c] + zd * dtb[r];
        }
        __syncthreads();
        if (t < FB_R * LD) zbuf[r][c] = zn;
        __syncthreads();
    }
    {
        const int c0 = t, c1 = t + 256;
        float acc0[FB_R], acc1[FB_R];
#pragma unroll
        for (int r = 0; r < FB_R; ++r) { acc0[r] = 0.f; acc1[r] = 0.f; }
#pragma unroll
        for (int k = 0; k < LD; ++k) {
            const float w0 = dW1[k * H + c0], w1 = dW1[k * H + c1];
#pragma unroll
            for (int r = 0; r < FB_R; ++r) {
                const float zv = zbuf[r][k];
                acc0[r] += zv * w0;
                acc1[r] += zv * w1;
            }
        }
        const float b0 = db1[c0], b1v = db1[c1];
#pragma unroll
        for (int r = 0; r < FB_R; ++r) {
            sA[r][c0] = acc0[r] + b0;
            sA[r][c1] = acc1[r] + b1v;
        }
    }
    __syncthreads();
    fb_ln_silu(sA, dg1, dbe1, t);
    __syncthreads();
    fb_gemmK<H>(sA, sB, dW2, db2, t);
    __syncthreads();
    fb_ln_silu(sB, dg2, dbe2, t);
    __syncthreads();
    {
        const int c = t & 63;
        const int rb = t >> 6;
        float acc[4] = {0.f, 0.f, 0.f, 0.f};
        for (int k = 0; k < H; k += 4) {
            const float w0 = dW3[(k + 0) * NX + c];
            const float w1 = dW3[(k + 1) * NX + c];
            const float w2 = dW3[(k + 2) * NX + c];
            const float w3 = dW3[(k + 3) * NX + c];
#pragma unroll
            for (int i = 0; i < 4; ++i) {
                const int r = rb + 4 * i;
                const float4 h = *(const float4*)&sB[r][k];
                acc[i] += h.x * w0 + h.y * w1 + h.z * w2 + h.w * w3;
            }
        }
        const float bb = db3[c];
#pragma unroll
        for (int i = 0; i < 4; ++i) {
            const int r = rb + 4 * i;
            out[(row0 + r) * NX + c] = acc[i] + bb;
        }
    }
}

extern "C" void kernel_launch(void* const* d_in, const int* in_sizes, int n_in,
                              void* d_out, int out_size, void* d_ws, size_t ws_size,
                              hipStream_t stream) {
    const float* x0    = (const float*)d_in[0];
    const float* logdt = (const float*)d_in[1];
    const float* eW1  = (const float*)d_in[4];
    const float* eb1  = (const float*)d_in[5];
    const float* eg1  = (const float*)d_in[6];
    const float* ebe1 = (const float*)d_in[7];
    const float* eW2  = (const float*)d_in[8];
    const float* eb2  = (const float*)d_in[9];
    const float* eg2  = (const float*)d_in[10];
    const float* ebe2 = (const float*)d_in[11];
    const float* eW3  = (const float*)d_in[12];
    const float* eb3  = (const float*)d_in[13];
    const float* dW1  = (const float*)d_in[14];
    const float* db1  = (const float*)d_in[15];
    const float* dg1  = (const float*)d_in[16];
    const float* dbe1 = (const float*)d_in[17];
    const float* dW2  = (const float*)d_in[18];
    const float* db2  = (const float*)d_in[19];
    const float* dg2  = (const float*)d_in[20];
    const float* dbe2 = (const float*)d_in[21];
    const float* dW3  = (const float*)d_in[22];
    const float* db3  = (const float*)d_in[23];
    const float* Xi   = (const float*)d_in[24];
    float* out = (float*)d_out;

    if (ws_size >= WS_NEW_BYTES) {
        short* wsb = (short*)d_ws;
        float* zt = (float*)((char*)d_ws + ZT_OFF_BYTES);
        prep_weights<<<WS_ALL / 256, 256, 0, stream>>>(eW1, eW2, dW2, dW3, eW3, dW1, wsb);
        sindy_enc_kernel<<<B_TOTAL / BM, NTH, 0, stream>>>(
            x0, logdt, eb1, eg1, ebe1, eb2, eg2, ebe2, eb3, Xi, wsb, zt);
        sindy_dec_kernel<<<B_TOTAL / BM, NTH, 0, stream>>>(
            zt, db1, dg1, dbe1, db2, dg2, dbe2, db3, wsb, out);
    } else {
        sindy_fallback_kernel<<<B_TOTAL / FB_R, FB_NT, 0, stream>>>(
            x0, logdt, eW1, eb1, eg1, ebe1, eW2, eb2, eg2, ebe2, eW3, eb3,
            dW1, db1, dg1, dbe1, dW2, db2, dg2, dbe2, dW3, db3, Xi, out);
    }
}

// Round 10
// 481.835 us; speedup vs baseline: 1.2542x; 1.2542x over previous
//
#include <hip/hip_runtime.h>
#include <hip/hip_bf16.h>
#include <math.h>

#define B_TOTAL 131072
#define NX 64
#define H 512
#define LD 8
#define NT 45          // 1 + 8 + 36
#define NSTEPS 20

#define NTH 512        // 8 waves
#define BM 64          // rows per block
#define ASTR 520       // bf16 elements per activation row (1040B stride: 2-way bank alias only)

// ws layout (bf16 elements). GEMM weights are K-CHUNKED: W[kc][n][32], chunk = 32 k-elems.
#define OFF_EW1T 0                    // [2][512][32]   (K=64)
#define OFF_EW2T 32768                // [16][512][32]
#define OFF_DW2T 294912               // [16][512][32]
#define OFF_DW3T 557056               // [16][64][32]
#define WS_ELEMS 589824
#define OFF_W3HI 589824               // [16][512] flat: bf16 hi part of eW3^T (rows 8..15 zero)
#define OFF_W3LO 598016               // [16][512] flat: lo correction
#define WS_ELEMS2 606208
#define OFF_DW1P 606208               // [512][32] hi/lo packed dW1 panel: slots [wh|wl|wh|wl]
#define WS_ELEMS3 622592              // * 2 bytes
#define ZT_OFF_BYTES (WS_ELEMS3 * 2)
#define WS_NEW_BYTES (ZT_OFF_BYTES + (size_t)B_TOTAL * LD * 4)

typedef __attribute__((ext_vector_type(8))) short short8;
typedef __attribute__((ext_vector_type(4))) float f32x4;

__device__ __forceinline__ ushort f2bf(float f) {
    union { float f; uint u; } v; v.f = f;
    uint u = v.u;
    u += 0x7fff + ((u >> 16) & 1);          // RNE
    return (ushort)(u >> 16);
}
__device__ __forceinline__ float bf2f(ushort s) {
    union { uint u; float f; } v; v.u = ((uint)s) << 16;
    return v.f;
}
__device__ __forceinline__ float silu_f(float v) {
    return v / (1.0f + __expf(-v));
}

// ---------------- weight prep: fp32 row-major [k][n] -> bf16 chunked W^T [kc][n][32] ----------------
__global__ void prep_weights(const float* __restrict__ eW1, const float* __restrict__ eW2,
                             const float* __restrict__ dW2, const float* __restrict__ dW3,
                             const float* __restrict__ eW3, const float* __restrict__ dW1,
                             short* __restrict__ ws) {
    const int id = blockIdx.x * 256 + threadIdx.x;
    if (id < OFF_EW2T) {                               // eW1c [2][512][32]
        const int kc = id >> 14, n = (id >> 5) & 511, kk = id & 31;
        ws[id] = (short)f2bf(eW1[(kc * 32 + kk) * H + n]);
    } else if (id < OFF_DW2T) {                        // eW2c [16][512][32]
        const int j = id - OFF_EW2T;
        const int kc = j >> 14, n = (j >> 5) & 511, kk = j & 31;
        ws[id] = (short)f2bf(eW2[(kc * 32 + kk) * H + n]);
    } else if (id < OFF_DW3T) {                        // dW2c [16][512][32]
        const int j = id - OFF_DW2T;
        const int kc = j >> 14, n = (j >> 5) & 511, kk = j & 31;
        ws[id] = (short)f2bf(dW2[(kc * 32 + kk) * H + n]);
    } else if (id < WS_ELEMS) {                        // dW3c [16][64][32]
        const int j = id - OFF_DW3T;
        const int kc = j >> 11, n = (j >> 5) & 63, kk = j & 31;
        ws[id] = (short)f2bf(dW3[(kc * 32 + kk) * NX + n]);
    } else if (id < OFF_W3LO) {                        // eW3T hi [16][512] flat
        const int j = id - OFF_W3HI, n = j >> 9, k = j & 511;
        const float v = (n < LD) ? eW3[k * LD + n] : 0.f;
        ws[id] = (short)f2bf(v);
    } else if (id < WS_ELEMS2) {                       // eW3T lo
        const int j = id - OFF_W3LO, n = j >> 9, k = j & 511;
        const float v = (n < LD) ? eW3[k * LD + n] : 0.f;
        const float hi = bf2f(f2bf(v));
        ws[id] = (short)f2bf(v - hi);
    } else if (id < WS_ELEMS3) {                       // dW1 packed [512][32]: k-slots [wh|wl|wh|wl]
        const int j = id - OFF_DW1P;
        const int n = j >> 5, s = j & 31;
        const int k = s & 7;
        const float v = dW1[k * H + n];
        const ushort hi = f2bf(v);
        ws[id] = (((s >> 3) & 1) == 0) ? (short)hi : (short)f2bf(v - bf2f(hi));
    }
}

// ---------------- GEMM: act[64][K] (LDS bf16) x W(KxN) via chunked W^T; 1x8 wave grid ----------------
// Wave w owns all 64 rows x cols [w*64, w*64+64): B loaded ONCE per block, contiguous 1KB segments.
// SINGLE-buffered B (b[4] = 32 arch regs): arch pressure ~55 < 64 (128 unified - 64 AGPR acc)
// at launch_bounds(512,4). Latency hiding via TLP (16 waves/CU), not register ping-pong.
template <int K, int N>
__device__ __forceinline__ void gemm_chunked(const short (*act)[ASTR], const short* __restrict__ WTc,
                                             f32x4 (&acc)[4][4], int w, int lm, int q) {
    constexpr int NC = K / 32;
    constexpr int CS = N * 32;
    const short* bp = WTc + (w * 64 + lm) * 32 + q * 8;
#pragma unroll 1
    for (int kc = 0; kc < NC; ++kc) {
        short8 b[4];
        const short* p = bp + kc * CS;
#pragma unroll
        for (int tt = 0; tt < 4; ++tt) b[tt] = *(const short8*)(p + tt * 512);
        const int k0 = kc * 32 + q * 8;
#pragma unroll
        for (int mt = 0; mt < 4; ++mt) {
            short8 a = *(const short8*)&act[mt * 16 + lm][k0];
#pragma unroll
            for (int tt = 0; tt < 4; ++tt)
                acc[mt][tt] = __builtin_amdgcn_mfma_f32_16x16x32_bf16(a, b[tt], acc[mt][tt], 0, 0, 0);
        }
    }
}

// ---------------- bias + LayerNorm + SiLU epilogue, 1x8 grid, per-mt sums (low reg pressure) ----------------
// C-layout: value (row = mt*16 + q*4 + r, col = w*64 + tt*16 + lm). In-place safe (stores after barriers).
__device__ __forceinline__ void ln_epi64(f32x4 (&acc)[4][4],
        const float* __restrict__ bias, const float* __restrict__ g, const float* __restrict__ be,
        short (*act)[ASTR], float (*p1)[8], float (*p2)[8], float (*rstat)[2],
        int w, int lane, int tid) {
    const int lm = lane & 15, q = lane >> 4;
    float cb[4], cg[4], cbe[4];
#pragma unroll
    for (int tt = 0; tt < 4; ++tt) {
        const int c = w * 64 + tt * 16 + lm;
        cb[tt] = bias[c]; cg[tt] = g[c]; cbe[tt] = be[c];
    }
#pragma unroll
    for (int mt = 0; mt < 4; ++mt) {
        float s1[4] = {0.f, 0.f, 0.f, 0.f}, s2[4] = {0.f, 0.f, 0.f, 0.f};
#pragma unroll
        for (int tt = 0; tt < 4; ++tt)
#pragma unroll
            for (int r = 0; r < 4; ++r) {
                float v = acc[mt][tt][r] + cb[tt];
                acc[mt][tt][r] = v;
                s1[r] += v;
                s2[r] += v * v;
            }
#pragma unroll
        for (int m = 1; m < 16; m <<= 1) {
#pragma unroll
            for (int r = 0; r < 4; ++r) {
                s1[r] += __shfl_xor(s1[r], m);
                s2[r] += __shfl_xor(s2[r], m);
            }
        }
        if (lm == 0) {
#pragma unroll
            for (int r = 0; r < 4; ++r) {
                const int row = mt * 16 + q * 4 + r;
                p1[row][w] = s1[r];
                p2[row][w] = s2[r];
            }
        }
    }
    __syncthreads();
    if (tid < BM) {
        float a = 0.f, b2 = 0.f;
#pragma unroll
        for (int j = 0; j < 8; ++j) { a += p1[tid][j]; b2 += p2[tid][j]; }
        const float mean = a * (1.0f / H);
        rstat[tid][0] = mean;
        rstat[tid][1] = rsqrtf(b2 * (1.0f / H) - mean * mean + 1e-5f);
    }
    __syncthreads();
#pragma unroll
    for (int mt = 0; mt < 4; ++mt) {
#pragma unroll
        for (int r = 0; r < 4; ++r) {
            const int row = mt * 16 + q * 4 + r;
            const float mu = rstat[row][0], rs = rstat[row][1];
#pragma unroll
            for (int tt = 0; tt < 4; ++tt) {
                const float v = (acc[mt][tt][r] - mu) * rs * cg[tt] + cbe[tt];
                act[row][w * 64 + tt * 16 + lm] = (short)f2bf(silu_f(v));
            }
        }
    }
    __syncthreads();
}

// ==================== K1: x0 -> encoder -> Euler -> z_t ====================
__global__ __launch_bounds__(NTH, 4) void sindy_enc_kernel(
        const float* __restrict__ x0, const float* __restrict__ logdt,
        const float* __restrict__ eb1, const float* __restrict__ eg1, const float* __restrict__ ebe1,
        const float* __restrict__ eb2, const float* __restrict__ eg2, const float* __restrict__ ebe2,
        const float* __restrict__ eb3, const float* __restrict__ Xi,
        const short* __restrict__ wsb, float* __restrict__ zt) {
    __shared__ __align__(16) short act[BM][ASTR];          // 66,560 B
    __shared__ __align__(16) float scratch[2048];          // 8 KB: p1|p2 or partial[4][64][8]
    __shared__ float rstat[BM][2];
    __shared__ float dtb[BM];
    __shared__ float xis[NT * LD];
    float (*p1)[8] = (float(*)[8])scratch;                       // [64][8]
    float (*p2)[8] = (float(*)[8])(scratch + 512);               // [64][8]
    float (*partial)[BM][LD] = (float(*)[BM][LD])scratch;        // [4][64][8] (time-disjoint)

    const int tid = threadIdx.x;
    const int w = tid >> 6, lane = tid & 63, lm = lane & 15, q = lane >> 4;
    const int row0 = blockIdx.x * BM;

    if (tid < NT * LD) xis[tid] = Xi[tid];
    if (tid < BM) dtb[tid] = logdt[row0 + tid] * (1.0f / NSTEPS);
    {   // stage x0 tile fp32 -> bf16 LDS (64 rows x 64 cols), coalesced
        const int r = tid >> 3, c8 = (tid & 7) * 8;
        const float* xr = &x0[(row0 + r) * NX + c8];
        const float4 va = *(const float4*)xr;
        const float4 vb = *(const float4*)(xr + 4);
        short8 sv;
        sv[0] = (short)f2bf(va.x); sv[1] = (short)f2bf(va.y);
        sv[2] = (short)f2bf(va.z); sv[3] = (short)f2bf(va.w);
        sv[4] = (short)f2bf(vb.x); sv[5] = (short)f2bf(vb.y);
        sv[6] = (short)f2bf(vb.z); sv[7] = (short)f2bf(vb.w);
        *(short8*)&act[r][c8] = sv;
    }
    __syncthreads();

    // ---- enc1: 64 -> 512 ----
    {
        f32x4 acc[4][4];
#pragma unroll
        for (int mt = 0; mt < 4; ++mt)
#pragma unroll
            for (int tt = 0; tt < 4; ++tt) acc[mt][tt] = (f32x4){0.f, 0.f, 0.f, 0.f};
        gemm_chunked<NX, H>(act, wsb + OFF_EW1T, acc, w, lm, q);
        ln_epi64(acc, eb1, eg1, ebe1, act, p1, p2, rstat, w, lane, tid);
    }

    // ---- enc2: 512 -> 512 ----
    {
        f32x4 acc[4][4];
#pragma unroll
        for (int mt = 0; mt < 4; ++mt)
#pragma unroll
            for (int tt = 0; tt < 4; ++tt) acc[mt][tt] = (f32x4){0.f, 0.f, 0.f, 0.f};
        gemm_chunked<H, H>(act, wsb + OFF_EW2T, acc, w, lm, q);
        ln_epi64(acc, eb2, eg2, ebe2, act, p1, p2, rstat, w, lane, tid);
    }

    // ---- enc3: 512 -> 8 via MFMA, hi/lo bf16 weight split (~fp32 weight precision) ----
    // wave w: kq = w&3 (128 k), mh = w>>2 (2 m-tile pairs). 16 MFMA/wave.
    float z0;
    {
        const short* W3H = wsb + OFF_W3HI;
        const short* W3L = wsb + OFF_W3LO;
        const int kq = w & 3, mh = w >> 2;
        f32x4 a3[2];
        a3[0] = (f32x4){0.f, 0.f, 0.f, 0.f};
        a3[1] = (f32x4){0.f, 0.f, 0.f, 0.f};
#pragma unroll
        for (int kc = 0; kc < 4; ++kc) {
            const int k0 = kq * 128 + kc * 32 + q * 8;
            short8 bh = *(const short8*)&W3H[lm * H + k0];
            short8 bl = *(const short8*)&W3L[lm * H + k0];
#pragma unroll
            for (int i = 0; i < 2; ++i) {
                short8 a = *(const short8*)&act[(mh * 2 + i) * 16 + lm][k0];
                a3[i] = __builtin_amdgcn_mfma_f32_16x16x32_bf16(a, bh, a3[i], 0, 0, 0);
                a3[i] = __builtin_amdgcn_mfma_f32_16x16x32_bf16(a, bl, a3[i], 0, 0, 0);
            }
        }
        if (lm < 8) {
#pragma unroll
            for (int i = 0; i < 2; ++i)
#pragma unroll
                for (int r = 0; r < 4; ++r)
                    partial[kq][(mh * 2 + i) * 16 + q * 4 + r][lm] = a3[i][r];
        }
        __syncthreads();
        {
            const int r = tid >> 3, c = tid & 7;
            const float s = partial[0][r][c] + partial[1][r][c] +
                            partial[2][r][c] + partial[3][r][c];
            z0 = tanhf(s + eb3[c]);
        }
    }

    // ---- SINDy Euler: barrier-free; linear coeffs in regs, quad coeffs from LDS ----
    // 4 independent accumulators break the ~80-FMA serial chain (~4x shorter critical path).
    {
        const int r = tid >> 3, c = tid & 7;
        const int lbase = lane & ~7;
        float xrl[1 + LD];
#pragma unroll
        for (int t = 0; t <= LD; ++t) xrl[t] = xis[t * LD + c];
        const float dtv = dtb[r];
        float zc = z0;
        for (int st = 0; st < NSTEPS; ++st) {
            float z[LD];
#pragma unroll
            for (int j = 0; j < LD; ++j) z[j] = __shfl(zc, lbase + j);
            float s0 = xrl[0], sA = 0.f, sB = 0.f, sC = 0.f;
#pragma unroll
            for (int j = 0; j < LD; j += 4) {
                s0 += z[j + 0] * xrl[1 + j + 0];
                sA += z[j + 1] * xrl[1 + j + 1];
                sB += z[j + 2] * xrl[1 + j + 2];
                sC += z[j + 3] * xrl[1 + j + 3];
            }
            int idx = 1 + LD;
#pragma unroll
            for (int i = 0; i < LD; ++i)
#pragma unroll
                for (int j = i; j < LD; ++j) {
                    const float p = z[i] * z[j];
                    switch (idx & 3) {
                        case 0: s0 += p * xis[idx * LD + c]; break;
                        case 1: sA += p * xis[idx * LD + c]; break;
                        case 2: sB += p * xis[idx * LD + c]; break;
                        default: sC += p * xis[idx * LD + c]; break;
                    }
                    ++idx;
                }
            zc += ((s0 + sA) + (sB + sC)) * dtv;
        }
        zt[row0 * LD + tid] = zc;   // coalesced
    }
}

// ==================== K2: z_t -> decoder -> out ====================
__global__ __launch_bounds__(NTH, 4) void sindy_dec_kernel(
        const float* __restrict__ zt,
        const float* __restrict__ db1,
        const float* __restrict__ dg1, const float* __restrict__ dbe1,
        const float* __restrict__ db2, const float* __restrict__ dg2, const float* __restrict__ dbe2,
        const float* __restrict__ db3,
        const short* __restrict__ wsb, float* __restrict__ out) {
    __shared__ __align__(16) short act[BM][ASTR];
    __shared__ float p1[BM][8], p2[BM][8], rstat[BM][2];
    __shared__ __align__(16) float zbuf[BM][LD];
    const int tid = threadIdx.x;
    const int w = tid >> 6, lane = tid & 63, lm = lane & 15, q = lane >> 4;
    const int row0 = blockIdx.x * BM;

    ((float*)zbuf)[tid] = zt[row0 * LD + tid];
    __syncthreads();

    // ---- dec1: 8 -> 512 via MFMA, hi/lo packed K=32 frags (~fp32 precision) ----
    // A = [zh,zh,zl,zl] (q selects), B = [wh,wl,wh,wl] -> sum = (zh+zl)(wh+wl) ~= z*w exactly.
    {
        const short* bp = wsb + OFF_DW1P + (w * 64 + lm) * 32 + q * 8;
        short8 b[4];
#pragma unroll
        for (int tt = 0; tt < 4; ++tt) b[tt] = *(const short8*)(bp + tt * 512);
        f32x4 acc[4][4];
#pragma unroll
        for (int mt = 0; mt < 4; ++mt) {
            const int row = mt * 16 + lm;
            const float4 za = *(const float4*)&zbuf[row][0];
            const float4 zb = *(const float4*)&zbuf[row][4];
            float zv[LD] = {za.x, za.y, za.z, za.w, zb.x, zb.y, zb.z, zb.w};
            short8 a;
#pragma unroll
            for (int j = 0; j < LD; ++j) {
                const ushort h = f2bf(zv[j]);
                a[j] = (q < 2) ? (short)h : (short)f2bf(zv[j] - bf2f(h));
            }
#pragma unroll
            for (int tt = 0; tt < 4; ++tt)
                acc[mt][tt] = __builtin_amdgcn_mfma_f32_16x16x32_bf16(
                    a, b[tt], (f32x4){0.f, 0.f, 0.f, 0.f}, 0, 0, 0);
        }
        ln_epi64(acc, db1, dg1, dbe1, act, p1, p2, rstat, w, lane, tid);
    }

    // ---- dec2: 512 -> 512 ----
    {
        f32x4 acc[4][4];
#pragma unroll
        for (int mt = 0; mt < 4; ++mt)
#pragma unroll
            for (int tt = 0; tt < 4; ++tt) acc[mt][tt] = (f32x4){0.f, 0.f, 0.f, 0.f};
        gemm_chunked<H, H>(act, wsb + OFF_DW2T, acc, w, lm, q);
        ln_epi64(acc, db2, dg2, dbe2, act, p1, p2, rstat, w, lane, tid);
    }

    // ---- dec3: 512 -> 64 + bias, fp32 out. wave w: nt = w&3, rows (w>>2)*32..+31 ----
    {
        const short* W3c = wsb + OFF_DW3T;
        const int nt = w & 3, mtb = (w >> 2) << 1;
        const short* bp = W3c + (nt * 16 + lm) * 32 + q * 8;
        f32x4 a2[2];
        a2[0] = (f32x4){0.f, 0.f, 0.f, 0.f};
        a2[1] = (f32x4){0.f, 0.f, 0.f, 0.f};
#pragma unroll 2
        for (int kc = 0; kc < 16; ++kc) {
            short8 b = *(const short8*)(bp + kc * 2048);
            const int k0 = kc * 32 + q * 8;
#pragma unroll
            for (int i = 0; i < 2; ++i) {
                short8 a = *(const short8*)&act[(mtb + i) * 16 + lm][k0];
                a2[i] = __builtin_amdgcn_mfma_f32_16x16x32_bf16(a, b, a2[i], 0, 0, 0);
            }
        }
        const int c = nt * 16 + lm;
        const float bb = db3[c];
#pragma unroll
        for (int i = 0; i < 2; ++i)
#pragma unroll
            for (int r = 0; r < 4; ++r) {
                const int row = (mtb + i) * 16 + q * 4 + r;
                out[(row0 + row) * NX + c] = a2[i][r] + bb;
            }
    }
}

// =================== fallback (fp32 kernel, no ws needed) ===================
#define FB_R 16
#define FB_STRIDE 520
#define FB_NT 256

__device__ __forceinline__ void fb_ln_silu(float buf[FB_R][FB_STRIDE],
                                           const float* __restrict__ g,
                                           const float* __restrict__ be, int t) {
    const int r = t >> 4, lane = t & 15;
    float s1 = 0.f, s2 = 0.f;
#pragma unroll
    for (int j = 0; j < H / 16; ++j) {
        float v = buf[r][lane + 16 * j];
        s1 += v; s2 += v * v;
    }
#pragma unroll
    for (int m = 8; m >= 1; m >>= 1) {
        s1 += __shfl_xor(s1, m, 16);
        s2 += __shfl_xor(s2, m, 16);
    }
    const float mean = s1 * (1.0f / H);
    const float var = s2 * (1.0f / H) - mean * mean;
    const float rstd = rsqrtf(var + 1e-5f);
#pragma unroll
    for (int j = 0; j < H / 16; ++j) {
        const int c = lane + 16 * j;
        float v = buf[r][c];
        buf[r][c] = silu_f((v - mean) * rstd * g[c] + be[c]);
    }
}

template <int K>
__device__ __forceinline__ void fb_gemmK(const float in[FB_R][FB_STRIDE], float out[FB_R][FB_STRIDE],
                                         const float* __restrict__ W,
                                         const float* __restrict__ b, int t) {
    const int c0 = t, c1 = t + 256;
    float acc0[FB_R], acc1[FB_R];
#pragma unroll
    for (int r = 0; r < FB_R; ++r) { acc0[r] = 0.f; acc1[r] = 0.f; }
    for (int k = 0; k < K; k += 4) {
        const float w00 = W[(k + 0) * H + c0], w10 = W[(k + 0) * H + c1];
        const float w01 = W[(k + 1) * H + c0], w11 = W[(k + 1) * H + c1];
        const float w02 = W[(k + 2) * H + c0], w12 = W[(k + 2) * H + c1];
        const float w03 = W[(k + 3) * H + c0], w13 = W[(k + 3) * H + c1];
#pragma unroll
        for (int r = 0; r < FB_R; ++r) {
            const float4 h = *(const float4*)&in[r][k];
            acc0[r] += h.x * w00 + h.y * w01 + h.z * w02 + h.w * w03;
            acc1[r] += h.x * w10 + h.y * w11 + h.z * w12 + h.w * w13;
        }
    }
    const float b0 = b[c0], b1 = b[c1];
#pragma unroll
    for (int r = 0; r < FB_R; ++r) {
        out[r][c0] = acc0[r] + b0;
        out[r][c1] = acc1[r] + b1;
    }
}

__global__ __launch_bounds__(FB_NT, 2) void sindy_fallback_kernel(
    const float* __restrict__ x0, const float* __restrict__ logdt,
    const float* __restrict__ eW1, const float* __restrict__ eb1,
    const float* __restrict__ eg1, const float* __restrict__ ebe1,
    const float* __restrict__ eW2, const float* __restrict__ eb2,
    const float* __restrict__ eg2, const float* __restrict__ ebe2,
    const float* __restrict__ eW3, const float* __restrict__ eb3,
    const float* __restrict__ dW1, const float* __restrict__ db1,
    const float* __restrict__ dg1, const float* __restrict__ dbe1,
    const float* __restrict__ dW2, const float* __restrict__ db2,
    const float* __restrict__ dg2, const float* __restrict__ dbe2,
    const float* __restrict__ dW3, const float* __restrict__ db3,
    const float* __restrict__ Xi, float* __restrict__ out) {
    __shared__ float sA[FB_R][FB_STRIDE];
    __shared__ float sB[FB_R][FB_STRIDE];
    __shared__ float zbuf[FB_R][LD];
    __shared__ float dtb[FB_R];
    __shared__ float xis[NT * LD];

    const int t = threadIdx.x;
    const int row0 = blockIdx.x * FB_R;

    for (int i = t; i < NT * LD; i += FB_NT) xis[i] = Xi[i];
    if (t < FB_R) dtb[t] = logdt[row0 + t] * (1.0f / NSTEPS);
    {
        const int r = t >> 4, k4 = (t & 15) * 4;
        *(float4*)&sB[r][k4] = *(const float4*)&x0[(row0 + r) * NX + k4];
    }
    __syncthreads();
    fb_gemmK<NX>(sB, sA, eW1, eb1, t);
    __syncthreads();
    fb_ln_silu(sA, eg1, ebe1, t);
    __syncthreads();
    fb_gemmK<H>(sA, sB, eW2, eb2, t);
    __syncthreads();
    fb_ln_silu(sB, eg2, ebe2, t);
    __syncthreads();
    if (t < FB_R * LD) {
        const int r = t >> 3, c = t & 7;
        float acc = 0.f;
        for (int k = 0; k < H; k += 4) {
            const float4 h = *(const float4*)&sB[r][k];
            acc += h.x * eW3[(k + 0) * LD + c] + h.y * eW3[(k + 1) * LD + c] +
                   h.z * eW3[(k + 2) * LD + c] + h.w * eW3[(k + 3) * LD + c];
        }
        zbuf[r][c] = tanhf(acc + eb3[c]);
    }
    __syncthreads();
    for (int s = 0; s < NSTEPS; ++s) {
        float zn = 0.f;
        const int r = t >> 3, c = t & 7;
        if (t < FB_R * LD) {
            float z[LD];
#pragma unroll
            for (int j = 0; j < LD; ++j) z[j] = zbuf[r][j];
            float zd = xis[c];
#pragma unroll
            for (int j = 0; j < LD; ++j) zd += z[j] * xis[(1 + j) * LD + c];
            int idx = 1 + LD;
#pragma unroll
            for (int i = 0; i < LD; ++i)
#pragma unroll
                for (int j = i; j < LD; ++j) {
                    zd += z[i] * z[j] * xis[idx * LD + c];
                    ++idx;
                }
            zn = z[c] + zd * dtb[r];
        }
        __syncthreads();
        if (t < FB_R * LD) zbuf[r][c] = zn;
        __syncthreads();
    }
    {
        const int c0 = t, c1 = t + 256;
        float acc0[FB_R], acc1[FB_R];
#pragma unroll
        for (int r = 0; r < FB_R; ++r) { acc0[r] = 0.f; acc1[r] = 0.f; }
#pragma unroll
        for (int k = 0; k < LD; ++k) {
            const float w0 = dW1[k * H + c0], w1 = dW1[k * H + c1];
#pragma unroll
            for (int r = 0; r < FB_R; ++r) {
                const float zv = zbuf[r][k];
                acc0[r] += zv * w0;
                acc1[r] += zv * w1;
            }
        }
        const float b0 = db1[c0], b1v = db1[c1];
#pragma unroll
        for (int r = 0; r < FB_R; ++r) {
            sA[r][c0] = acc0[r] + b0;
            sA[r][c1] = acc1[r] + b1v;
        }
    }
    __syncthreads();
    fb_ln_silu(sA, dg1, dbe1, t);
    __syncthreads();
    fb_gemmK<H>(sA, sB, dW2, db2, t);
    __syncthreads();
    fb_ln_silu(sB, dg2, dbe2, t);
    __syncthreads();
    {
        const int c = t & 63;
        const int rb = t >> 6;
        float acc[4] = {0.f, 0.f, 0.f, 0.f};
        for (int k = 0; k < H; k += 4) {
            const float w0 = dW3[(k + 0) * NX + c];
            const float w1 = dW3[(k + 1) * NX + c];
            const float w2 = dW3[(k + 2) * NX + c];
            const float w3 = dW3[(k + 3) * NX + c];
#pragma unroll
            for (int i = 0; i < 4; ++i) {
                const int r = rb + 4 * i;
                const float4 h = *(const float4*)&sB[r][k];
                acc[i] += h.x * w0 + h.y * w1 + h.z * w2 + h.w * w3;
            }
        }
        const float bb = db3[c];
#pragma unroll
        for (int i = 0; i < 4; ++i) {
            const int r = rb + 4 * i;
            out[(row0 + r) * NX + c] = acc[i] + bb;
        }
    }
}

extern "C" void kernel_launch(void* const* d_in, const int* in_sizes, int n_in,
                              void* d_out, int out_size, void* d_ws, size_t ws_size,
                              hipStream_t stream) {
    const float* x0    = (const float*)d_in[0];
    const float* logdt = (const float*)d_in[1];
    const float* eW1  = (const float*)d_in[4];
    const float* eb1  = (const float*)d_in[5];
    const float* eg1  = (const float*)d_in[6];
    const float* ebe1 = (const float*)d_in[7];
    const float* eW2  = (const float*)d_in[8];
    const float* eb2  = (const float*)d_in[9];
    const float* eg2  = (const float*)d_in[10];
    const float* ebe2 = (const float*)d_in[11];
    const float* eW3  = (const float*)d_in[12];
    const float* eb3  = (const float*)d_in[13];
    const float* dW1  = (const float*)d_in[14];
    const float* db1  = (const float*)d_in[15];
    const float* dg1  = (const float*)d_in[16];
    const float* dbe1 = (const float*)d_in[17];
    const float* dW2  = (const float*)d_in[18];
    const float* db2  = (const float*)d_in[19];
    const float* dg2  = (const float*)d_in[20];
    const float* dbe2 = (const float*)d_in[21];
    const float* dW3  = (const float*)d_in[22];
    const float* db3  = (const float*)d_in[23];
    const float* Xi   = (const float*)d_in[24];
    float* out = (float*)d_out;

    if (ws_size >= WS_NEW_BYTES) {
        short* wsb = (short*)d_ws;
        float* zt = (float*)((char*)d_ws + ZT_OFF_BYTES);
        prep_weights<<<WS_ELEMS3 / 256, 256, 0, stream>>>(eW1, eW2, dW2, dW3, eW3, dW1, wsb);
        sindy_enc_kernel<<<B_TOTAL / BM, NTH, 0, stream>>>(
            x0, logdt, eb1, eg1, ebe1, eb2, eg2, ebe2, eb3, Xi, wsb, zt);
        sindy_dec_kernel<<<B_TOTAL / BM, NTH, 0, stream>>>(
            zt, db1, dg1, dbe1, db2, dg2, dbe2, db3, wsb, out);
    } else {
        sindy_fallback_kernel<<<B_TOTAL / FB_R, FB_NT, 0, stream>>>(
            x0, logdt, eW1, eb1, eg1, ebe1, eW2, eb2, eg2, ebe2, eW3, eb3,
            dW1, db1, dg1, dbe1, dW2, db2, dg2, dbe2, dW3, db3, Xi, out);
    }
}

// Round 11
// 469.887 us; speedup vs baseline: 1.2861x; 1.0254x over previous
//
#include <hip/hip_runtime.h>
#include <hip/hip_bf16.h>
#include <math.h>

#define B_TOTAL 131072
#define NX 64
#define H 512
#define LD 8
#define NT 45          // 1 + 8 + 36
#define NSTEPS 20

#define NTH 512        // 8 waves
#define BM 64          // rows per block
#define ASTR 520       // bf16 elements per activation row (1040B stride: 2-way bank alias only)

// ws layout (bf16 elements). GEMM weights are K-CHUNKED: W[kc][n][32], chunk = 32 k-elems.
#define OFF_EW1T 0                    // [2][512][32]   (K=64)
#define OFF_EW2T 32768                // [16][512][32]
#define OFF_DW2T 294912               // [16][512][32]
#define OFF_DW3T 557056               // [16][64][32]
#define WS_ELEMS 589824
#define OFF_W3HI 589824               // [16][512] flat: bf16 hi part of eW3^T (rows 8..15 zero)
#define OFF_W3LO 598016               // [16][512] flat: lo correction
#define WS_ELEMS2 606208
#define OFF_DW1P 606208               // [512][32] hi/lo packed dW1 panel: slots [wh|wl|wh|wl]
#define WS_ELEMS3 622592              // * 2 bytes
#define ZT_OFF_BYTES (WS_ELEMS3 * 2)
#define WS_NEW_BYTES (ZT_OFF_BYTES + (size_t)B_TOTAL * LD * 4)

typedef __attribute__((ext_vector_type(8))) short short8;
typedef __attribute__((ext_vector_type(4))) float f32x4;

__device__ __forceinline__ ushort f2bf(float f) {
    union { float f; uint u; } v; v.f = f;
    uint u = v.u;
    u += 0x7fff + ((u >> 16) & 1);          // RNE
    return (ushort)(u >> 16);
}
__device__ __forceinline__ float bf2f(ushort s) {
    union { uint u; float f; } v; v.u = ((uint)s) << 16;
    return v.f;
}
__device__ __forceinline__ float silu_f(float v) {
    return v / (1.0f + __expf(-v));
}

// ---------------- weight prep: fp32 row-major [k][n] -> bf16 chunked W^T [kc][n][32] ----------------
__global__ void prep_weights(const float* __restrict__ eW1, const float* __restrict__ eW2,
                             const float* __restrict__ dW2, const float* __restrict__ dW3,
                             const float* __restrict__ eW3, const float* __restrict__ dW1,
                             short* __restrict__ ws) {
    const int id = blockIdx.x * 256 + threadIdx.x;
    if (id < OFF_EW2T) {                               // eW1c [2][512][32]
        const int kc = id >> 14, n = (id >> 5) & 511, kk = id & 31;
        ws[id] = (short)f2bf(eW1[(kc * 32 + kk) * H + n]);
    } else if (id < OFF_DW2T) {                        // eW2c [16][512][32]
        const int j = id - OFF_EW2T;
        const int kc = j >> 14, n = (j >> 5) & 511, kk = j & 31;
        ws[id] = (short)f2bf(eW2[(kc * 32 + kk) * H + n]);
    } else if (id < OFF_DW3T) {                        // dW2c [16][512][32]
        const int j = id - OFF_DW2T;
        const int kc = j >> 14, n = (j >> 5) & 511, kk = j & 31;
        ws[id] = (short)f2bf(dW2[(kc * 32 + kk) * H + n]);
    } else if (id < WS_ELEMS) {                        // dW3c [16][64][32]
        const int j = id - OFF_DW3T;
        const int kc = j >> 11, n = (j >> 5) & 63, kk = j & 31;
        ws[id] = (short)f2bf(dW3[(kc * 32 + kk) * NX + n]);
    } else if (id < OFF_W3LO) {                        // eW3T hi [16][512] flat
        const int j = id - OFF_W3HI, n = j >> 9, k = j & 511;
        const float v = (n < LD) ? eW3[k * LD + n] : 0.f;
        ws[id] = (short)f2bf(v);
    } else if (id < WS_ELEMS2) {                       // eW3T lo
        const int j = id - OFF_W3LO, n = j >> 9, k = j & 511;
        const float v = (n < LD) ? eW3[k * LD + n] : 0.f;
        const float hi = bf2f(f2bf(v));
        ws[id] = (short)f2bf(v - hi);
    } else if (id < WS_ELEMS3) {                       // dW1 packed [512][32]: k-slots [wh|wl|wh|wl]
        const int j = id - OFF_DW1P;
        const int n = j >> 5, s = j & 31;
        const int k = s & 7;
        const float v = dW1[k * H + n];
        const ushort hi = f2bf(v);
        ws[id] = (((s >> 3) & 1) == 0) ? (short)hi : (short)f2bf(v - bf2f(hi));
    }
}

// ---------------- GEMM: act[64][K] (LDS bf16) x W(KxN) via chunked W^T; 1x8 wave grid ----------------
// Wave w owns all 64 rows x cols [w*64, w*64+64): B loaded ONCE per block, contiguous 1KB segments.
// SINGLE-buffered B (b[4] = 32 arch regs): arch pressure ~55 < 64 (128 unified - 64 AGPR acc)
// at launch_bounds(512,4). Latency hiding via TLP (16 waves/CU), not register ping-pong.
template <int K, int N>
__device__ __forceinline__ void gemm_chunked(const short (*act)[ASTR], const short* __restrict__ WTc,
                                             f32x4 (&acc)[4][4], int w, int lm, int q) {
    constexpr int NC = K / 32;
    constexpr int CS = N * 32;
    const short* bp = WTc + (w * 64 + lm) * 32 + q * 8;
#pragma unroll 1
    for (int kc = 0; kc < NC; ++kc) {
        short8 b[4];
        const short* p = bp + kc * CS;
#pragma unroll
        for (int tt = 0; tt < 4; ++tt) b[tt] = *(const short8*)(p + tt * 512);
        const int k0 = kc * 32 + q * 8;
#pragma unroll
        for (int mt = 0; mt < 4; ++mt) {
            short8 a = *(const short8*)&act[mt * 16 + lm][k0];
#pragma unroll
            for (int tt = 0; tt < 4; ++tt)
                acc[mt][tt] = __builtin_amdgcn_mfma_f32_16x16x32_bf16(a, b[tt], acc[mt][tt], 0, 0, 0);
        }
    }
}

// ---------------- bias + LayerNorm + SiLU epilogue, 1x8 grid, per-mt sums (low reg pressure) ----------------
// C-layout: value (row = mt*16 + q*4 + r, col = w*64 + tt*16 + lm). In-place safe (stores after barriers).
__device__ __forceinline__ void ln_epi64(f32x4 (&acc)[4][4],
        const float* __restrict__ bias, const float* __restrict__ g, const float* __restrict__ be,
        short (*act)[ASTR], float (*p1)[8], float (*p2)[8], float (*rstat)[2],
        int w, int lane, int tid) {
    const int lm = lane & 15, q = lane >> 4;
    float cb[4], cg[4], cbe[4];
#pragma unroll
    for (int tt = 0; tt < 4; ++tt) {
        const int c = w * 64 + tt * 16 + lm;
        cb[tt] = bias[c]; cg[tt] = g[c]; cbe[tt] = be[c];
    }
#pragma unroll
    for (int mt = 0; mt < 4; ++mt) {
        float s1[4] = {0.f, 0.f, 0.f, 0.f}, s2[4] = {0.f, 0.f, 0.f, 0.f};
#pragma unroll
        for (int tt = 0; tt < 4; ++tt)
#pragma unroll
            for (int r = 0; r < 4; ++r) {
                float v = acc[mt][tt][r] + cb[tt];
                acc[mt][tt][r] = v;
                s1[r] += v;
                s2[r] += v * v;
            }
#pragma unroll
        for (int m = 1; m < 16; m <<= 1) {
#pragma unroll
            for (int r = 0; r < 4; ++r) {
                s1[r] += __shfl_xor(s1[r], m);
                s2[r] += __shfl_xor(s2[r], m);
            }
        }
        if (lm == 0) {
#pragma unroll
            for (int r = 0; r < 4; ++r) {
                const int row = mt * 16 + q * 4 + r;
                p1[row][w] = s1[r];
                p2[row][w] = s2[r];
            }
        }
    }
    __syncthreads();
    if (tid < BM) {
        float a = 0.f, b2 = 0.f;
#pragma unroll
        for (int j = 0; j < 8; ++j) { a += p1[tid][j]; b2 += p2[tid][j]; }
        const float mean = a * (1.0f / H);
        rstat[tid][0] = mean;
        rstat[tid][1] = rsqrtf(b2 * (1.0f / H) - mean * mean + 1e-5f);
    }
    __syncthreads();
#pragma unroll
    for (int mt = 0; mt < 4; ++mt) {
#pragma unroll
        for (int r = 0; r < 4; ++r) {
            const int row = mt * 16 + q * 4 + r;
            const float mu = rstat[row][0], rs = rstat[row][1];
#pragma unroll
            for (int tt = 0; tt < 4; ++tt) {
                const float v = (acc[mt][tt][r] - mu) * rs * cg[tt] + cbe[tt];
                act[row][w * 64 + tt * 16 + lm] = (short)f2bf(silu_f(v));
            }
        }
    }
    __syncthreads();
}

// ==================== K1: x0 -> encoder -> Euler -> z_t (exact R8 form: best measured 227 us) ====================
__global__ __launch_bounds__(NTH, 4) void sindy_enc_kernel(
        const float* __restrict__ x0, const float* __restrict__ logdt,
        const float* __restrict__ eb1, const float* __restrict__ eg1, const float* __restrict__ ebe1,
        const float* __restrict__ eb2, const float* __restrict__ eg2, const float* __restrict__ ebe2,
        const float* __restrict__ eb3, const float* __restrict__ Xi,
        const short* __restrict__ wsb, float* __restrict__ zt) {
    __shared__ __align__(16) short act[BM][ASTR];          // 66,560 B
    __shared__ __align__(16) float scratch[2048];          // 8 KB: p1|p2 or partial[4][64][8]
    __shared__ float rstat[BM][2];
    __shared__ float dtb[BM];
    __shared__ float xis[NT * LD];
    float (*p1)[8] = (float(*)[8])scratch;                       // [64][8]
    float (*p2)[8] = (float(*)[8])(scratch + 512);               // [64][8]
    float (*partial)[BM][LD] = (float(*)[BM][LD])scratch;        // [4][64][8] (time-disjoint)

    const int tid = threadIdx.x;
    const int w = tid >> 6, lane = tid & 63, lm = lane & 15, q = lane >> 4;
    const int row0 = blockIdx.x * BM;

    if (tid < NT * LD) xis[tid] = Xi[tid];
    if (tid < BM) dtb[tid] = logdt[row0 + tid] * (1.0f / NSTEPS);
    {   // stage x0 tile fp32 -> bf16 LDS (64 rows x 64 cols), coalesced
        const int r = tid >> 3, c8 = (tid & 7) * 8;
        const float* xr = &x0[(row0 + r) * NX + c8];
        const float4 va = *(const float4*)xr;
        const float4 vb = *(const float4*)(xr + 4);
        short8 sv;
        sv[0] = (short)f2bf(va.x); sv[1] = (short)f2bf(va.y);
        sv[2] = (short)f2bf(va.z); sv[3] = (short)f2bf(va.w);
        sv[4] = (short)f2bf(vb.x); sv[5] = (short)f2bf(vb.y);
        sv[6] = (short)f2bf(vb.z); sv[7] = (short)f2bf(vb.w);
        *(short8*)&act[r][c8] = sv;
    }
    __syncthreads();

    // ---- enc1: 64 -> 512 ----
    {
        f32x4 acc[4][4];
#pragma unroll
        for (int mt = 0; mt < 4; ++mt)
#pragma unroll
            for (int tt = 0; tt < 4; ++tt) acc[mt][tt] = (f32x4){0.f, 0.f, 0.f, 0.f};
        gemm_chunked<NX, H>(act, wsb + OFF_EW1T, acc, w, lm, q);
        ln_epi64(acc, eb1, eg1, ebe1, act, p1, p2, rstat, w, lane, tid);
    }

    // ---- enc2: 512 -> 512 ----
    {
        f32x4 acc[4][4];
#pragma unroll
        for (int mt = 0; mt < 4; ++mt)
#pragma unroll
            for (int tt = 0; tt < 4; ++tt) acc[mt][tt] = (f32x4){0.f, 0.f, 0.f, 0.f};
        gemm_chunked<H, H>(act, wsb + OFF_EW2T, acc, w, lm, q);
        ln_epi64(acc, eb2, eg2, ebe2, act, p1, p2, rstat, w, lane, tid);
    }

    // ---- enc3: 512 -> 8 via MFMA, hi/lo bf16 weight split (~fp32 weight precision) ----
    // wave w: kq = w&3 (128 k), mh = w>>2 (2 m-tile pairs). 16 MFMA/wave.
    float z0;
    {
        const short* W3H = wsb + OFF_W3HI;
        const short* W3L = wsb + OFF_W3LO;
        const int kq = w & 3, mh = w >> 2;
        f32x4 a3[2];
        a3[0] = (f32x4){0.f, 0.f, 0.f, 0.f};
        a3[1] = (f32x4){0.f, 0.f, 0.f, 0.f};
#pragma unroll
        for (int kc = 0; kc < 4; ++kc) {
            const int k0 = kq * 128 + kc * 32 + q * 8;
            short8 bh = *(const short8*)&W3H[lm * H + k0];
            short8 bl = *(const short8*)&W3L[lm * H + k0];
#pragma unroll
            for (int i = 0; i < 2; ++i) {
                short8 a = *(const short8*)&act[(mh * 2 + i) * 16 + lm][k0];
                a3[i] = __builtin_amdgcn_mfma_f32_16x16x32_bf16(a, bh, a3[i], 0, 0, 0);
                a3[i] = __builtin_amdgcn_mfma_f32_16x16x32_bf16(a, bl, a3[i], 0, 0, 0);
            }
        }
        if (lm < 8) {
#pragma unroll
            for (int i = 0; i < 2; ++i)
#pragma unroll
                for (int r = 0; r < 4; ++r)
                    partial[kq][(mh * 2 + i) * 16 + q * 4 + r][lm] = a3[i][r];
        }
        __syncthreads();
        {
            const int r = tid >> 3, c = tid & 7;
            const float s = partial[0][r][c] + partial[1][r][c] +
                            partial[2][r][c] + partial[3][r][c];
            z0 = tanhf(s + eb3[c]);
        }
    }

    // ---- SINDy Euler: barrier-free; linear coeffs in regs, quad coeffs from LDS (R8 form) ----
    {
        const int r = tid >> 3, c = tid & 7;
        const int lbase = lane & ~7;
        float xrl[1 + LD];
#pragma unroll
        for (int t = 0; t <= LD; ++t) xrl[t] = xis[t * LD + c];
        const float dtv = dtb[r];
        float zc = z0;
        for (int st = 0; st < NSTEPS; ++st) {
            float z[LD];
#pragma unroll
            for (int j = 0; j < LD; ++j) z[j] = __shfl(zc, lbase + j);
            float zd = xrl[0];
#pragma unroll
            for (int j = 0; j < LD; ++j) zd += z[j] * xrl[1 + j];
            int idx = 1 + LD;
#pragma unroll
            for (int i = 0; i < LD; ++i)
#pragma unroll
                for (int j = i; j < LD; ++j) {
                    zd += z[i] * z[j] * xis[idx * LD + c];
                    ++idx;
                }
            zc += zd * dtv;
        }
        zt[row0 * LD + tid] = zc;   // coalesced
    }
}

// ==================== K2: z_t -> decoder -> out (R10 form: best measured ~190 us) ====================
__global__ __launch_bounds__(NTH, 4) void sindy_dec_kernel(
        const float* __restrict__ zt,
        const float* __restrict__ db1,
        const float* __restrict__ dg1, const float* __restrict__ dbe1,
        const float* __restrict__ db2, const float* __restrict__ dg2, const float* __restrict__ dbe2,
        const float* __restrict__ db3,
        const short* __restrict__ wsb, float* __restrict__ out) {
    __shared__ __align__(16) short act[BM][ASTR];
    __shared__ float p1[BM][8], p2[BM][8], rstat[BM][2];
    __shared__ __align__(16) float zbuf[BM][LD];
    const int tid = threadIdx.x;
    const int w = tid >> 6, lane = tid & 63, lm = lane & 15, q = lane >> 4;
    const int row0 = blockIdx.x * BM;

    ((float*)zbuf)[tid] = zt[row0 * LD + tid];
    __syncthreads();

    // ---- dec1: 8 -> 512 via MFMA, hi/lo packed K=32 frags (~fp32 precision) ----
    // A = [zh,zh,zl,zl] (q selects), B = [wh,wl,wh,wl] -> sum = (zh+zl)(wh+wl) ~= z*w exactly.
    {
        const short* bp = wsb + OFF_DW1P + (w * 64 + lm) * 32 + q * 8;
        short8 b[4];
#pragma unroll
        for (int tt = 0; tt < 4; ++tt) b[tt] = *(const short8*)(bp + tt * 512);
        f32x4 acc[4][4];
#pragma unroll
        for (int mt = 0; mt < 4; ++mt) {
            const int row = mt * 16 + lm;
            const float4 za = *(const float4*)&zbuf[row][0];
            const float4 zb = *(const float4*)&zbuf[row][4];
            float zv[LD] = {za.x, za.y, za.z, za.w, zb.x, zb.y, zb.z, zb.w};
            short8 a;
#pragma unroll
            for (int j = 0; j < LD; ++j) {
                const ushort h = f2bf(zv[j]);
                a[j] = (q < 2) ? (short)h : (short)f2bf(zv[j] - bf2f(h));
            }
#pragma unroll
            for (int tt = 0; tt < 4; ++tt)
                acc[mt][tt] = __builtin_amdgcn_mfma_f32_16x16x32_bf16(
                    a, b[tt], (f32x4){0.f, 0.f, 0.f, 0.f}, 0, 0, 0);
        }
        ln_epi64(acc, db1, dg1, dbe1, act, p1, p2, rstat, w, lane, tid);
    }

    // ---- dec2: 512 -> 512 ----
    {
        f32x4 acc[4][4];
#pragma unroll
        for (int mt = 0; mt < 4; ++mt)
#pragma unroll
            for (int tt = 0; tt < 4; ++tt) acc[mt][tt] = (f32x4){0.f, 0.f, 0.f, 0.f};
        gemm_chunked<H, H>(act, wsb + OFF_DW2T, acc, w, lm, q);
        ln_epi64(acc, db2, dg2, dbe2, act, p1, p2, rstat, w, lane, tid);
    }

    // ---- dec3: 512 -> 64 + bias, fp32 out. wave w: nt = w&3, rows (w>>2)*32..+31 ----
    // unroll 2: one extra in-flight B load overlaps prior MFMAs (measured ~45 us win, no spill)
    {
        const short* W3c = wsb + OFF_DW3T;
        const int nt = w & 3, mtb = (w >> 2) << 1;
        const short* bp = W3c + (nt * 16 + lm) * 32 + q * 8;
        f32x4 a2[2];
        a2[0] = (f32x4){0.f, 0.f, 0.f, 0.f};
        a2[1] = (f32x4){0.f, 0.f, 0.f, 0.f};
#pragma unroll 2
        for (int kc = 0; kc < 16; ++kc) {
            short8 b = *(const short8*)(bp + kc * 2048);
            const int k0 = kc * 32 + q * 8;
#pragma unroll
            for (int i = 0; i < 2; ++i) {
                short8 a = *(const short8*)&act[(mtb + i) * 16 + lm][k0];
                a2[i] = __builtin_amdgcn_mfma_f32_16x16x32_bf16(a, b, a2[i], 0, 0, 0);
            }
        }
        const int c = nt * 16 + lm;
        const float bb = db3[c];
#pragma unroll
        for (int i = 0; i < 2; ++i)
#pragma unroll
            for (int r = 0; r < 4; ++r) {
                const int row = (mtb + i) * 16 + q * 4 + r;
                out[(row0 + row) * NX + c] = a2[i][r] + bb;
            }
    }
}

// =================== fallback (fp32 kernel, no ws needed) ===================
#define FB_R 16
#define FB_STRIDE 520
#define FB_NT 256

__device__ __forceinline__ void fb_ln_silu(float buf[FB_R][FB_STRIDE],
                                           const float* __restrict__ g,
                                           const float* __restrict__ be, int t) {
    const int r = t >> 4, lane = t & 15;
    float s1 = 0.f, s2 = 0.f;
#pragma unroll
    for (int j = 0; j < H / 16; ++j) {
        float v = buf[r][lane + 16 * j];
        s1 += v; s2 += v * v;
    }
#pragma unroll
    for (int m = 8; m >= 1; m >>= 1) {
        s1 += __shfl_xor(s1, m, 16);
        s2 += __shfl_xor(s2, m, 16);
    }
    const float mean = s1 * (1.0f / H);
    const float var = s2 * (1.0f / H) - mean * mean;
    const float rstd = rsqrtf(var + 1e-5f);
#pragma unroll
    for (int j = 0; j < H / 16; ++j) {
        const int c = lane + 16 * j;
        float v = buf[r][c];
        buf[r][c] = silu_f((v - mean) * rstd * g[c] + be[c]);
    }
}

template <int K>
__device__ __forceinline__ void fb_gemmK(const float in[FB_R][FB_STRIDE], float out[FB_R][FB_STRIDE],
                                         const float* __restrict__ W,
                                         const float* __restrict__ b, int t) {
    const int c0 = t, c1 = t + 256;
    float acc0[FB_R], acc1[FB_R];
#pragma unroll
    for (int r = 0; r < FB_R; ++r) { acc0[r] = 0.f; acc1[r] = 0.f; }
    for (int k = 0; k < K; k += 4) {
        const float w00 = W[(k + 0) * H + c0], w10 = W[(k + 0) * H + c1];
        const float w01 = W[(k + 1) * H + c0], w11 = W[(k + 1) * H + c1];
        const float w02 = W[(k + 2) * H + c0], w12 = W[(k + 2) * H + c1];
        const float w03 = W[(k + 3) * H + c0], w13 = W[(k + 3) * H + c1];
#pragma unroll
        for (int r = 0; r < FB_R; ++r) {
            const float4 h = *(const float4*)&in[r][k];
            acc0[r] += h.x * w00 + h.y * w01 + h.z * w02 + h.w * w03;
            acc1[r] += h.x * w10 + h.y * w11 + h.z * w12 + h.w * w13;
        }
    }
    const float b0 = b[c0], b1 = b[c1];
#pragma unroll
    for (int r = 0; r < FB_R; ++r) {
        out[r][c0] = acc0[r] + b0;
        out[r][c1] = acc1[r] + b1;
    }
}

__global__ __launch_bounds__(FB_NT, 2) void sindy_fallback_kernel(
    const float* __restrict__ x0, const float* __restrict__ logdt,
    const float* __restrict__ eW1, const float* __restrict__ eb1,
    const float* __restrict__ eg1, const float* __restrict__ ebe1,
    const float* __restrict__ eW2, const float* __restrict__ eb2,
    const float* __restrict__ eg2, const float* __restrict__ ebe2,
    const float* __restrict__ eW3, const float* __restrict__ eb3,
    const float* __restrict__ dW1, const float* __restrict__ db1,
    const float* __restrict__ dg1, const float* __restrict__ dbe1,
    const float* __restrict__ dW2, const float* __restrict__ db2,
    const float* __restrict__ dg2, const float* __restrict__ dbe2,
    const float* __restrict__ dW3, const float* __restrict__ db3,
    const float* __restrict__ Xi, float* __restrict__ out) {
    __shared__ float sA[FB_R][FB_STRIDE];
    __shared__ float sB[FB_R][FB_STRIDE];
    __shared__ float zbuf[FB_R][LD];
    __shared__ float dtb[FB_R];
    __shared__ float xis[NT * LD];

    const int t = threadIdx.x;
    const int row0 = blockIdx.x * FB_R;

    for (int i = t; i < NT * LD; i += FB_NT) xis[i] = Xi[i];
    if (t < FB_R) dtb[t] = logdt[row0 + t] * (1.0f / NSTEPS);
    {
        const int r = t >> 4, k4 = (t & 15) * 4;
        *(float4*)&sB[r][k4] = *(const float4*)&x0[(row0 + r) * NX + k4];
    }
    __syncthreads();
    fb_gemmK<NX>(sB, sA, eW1, eb1, t);
    __syncthreads();
    fb_ln_silu(sA, eg1, ebe1, t);
    __syncthreads();
    fb_gemmK<H>(sA, sB, eW2, eb2, t);
    __syncthreads();
    fb_ln_silu(sB, eg2, ebe2, t);
    __syncthreads();
    if (t < FB_R * LD) {
        const int r = t >> 3, c = t & 7;
        float acc = 0.f;
        for (int k = 0; k < H; k += 4) {
            const float4 h = *(const float4*)&sB[r][k];
            acc += h.x * eW3[(k + 0) * LD + c] + h.y * eW3[(k + 1) * LD + c] +
                   h.z * eW3[(k + 2) * LD + c] + h.w * eW3[(k + 3) * LD + c];
        }
        zbuf[r][c] = tanhf(acc + eb3[c]);
    }
    __syncthreads();
    for (int s = 0; s < NSTEPS; ++s) {
        float zn = 0.f;
        const int r = t >> 3, c = t & 7;
        if (t < FB_R * LD) {
            float z[LD];
#pragma unroll
            for (int j = 0; j < LD; ++j) z[j] = zbuf[r][j];
            float zd = xis[c];
#pragma unroll
            for (int j = 0; j < LD; ++j) zd += z[j] * xis[(1 + j) * LD + c];
            int idx = 1 + LD;
#pragma unroll
            for (int i = 0; i < LD; ++i)
#pragma unroll
                for (int j = i; j < LD; ++j) {
                    zd += z[i] * z[j] * xis[idx * LD + c];
                    ++idx;
                }
            zn = z[c] + zd * dtb[r];
        }
        __syncthreads();
        if (t < FB_R * LD) zbuf[r][c] = zn;
        __syncthreads();
    }
    {
        const int c0 = t, c1 = t + 256;
        float acc0[FB_R], acc1[FB_R];
#pragma unroll
        for (int r = 0; r < FB_R; ++r) { acc0[r] = 0.f; acc1[r] = 0.f; }
#pragma unroll
        for (int k = 0; k < LD; ++k) {
            const float w0 = dW1[k * H + c0], w1 = dW1[k * H + c1];
#pragma unroll
            for (int r = 0; r < FB_R; ++r) {
                const float zv = zbuf[r][k];
                acc0[r] += zv * w0;
                acc1[r] += zv * w1;
            }
        }
        const float b0 = db1[c0], b1v = db1[c1];
#pragma unroll
        for (int r = 0; r < FB_R; ++r) {
            sA[r][c0] = acc0[r] + b0;
            sA[r][c1] = acc1[r] + b1v;
        }
    }
    __syncthreads();
    fb_ln_silu(sA, dg1, dbe1, t);
    __syncthreads();
    fb_gemmK<H>(sA, sB, dW2, db2, t);
    __syncthreads();
    fb_ln_silu(sB, dg2, dbe2, t);
    __syncthreads();
    {
        const int c = t & 63;
        const int rb = t >> 6;
        float acc[4] = {0.f, 0.f, 0.f, 0.f};
        for (int k = 0; k < H; k += 4) {
            const float w0 = dW3[(k + 0) * NX + c];
            const float w1 = dW3[(k + 1) * NX + c];
            const float w2 = dW3[(k + 2) * NX + c];
            const float w3 = dW3[(k + 3) * NX + c];
#pragma unroll
            for (int i = 0; i < 4; ++i) {
                const int r = rb + 4 * i;
                const float4 h = *(const float4*)&sB[r][k];
                acc[i] += h.x * w0 + h.y * w1 + h.z * w2 + h.w * w3;
            }
        }
        const float bb = db3[c];
#pragma unroll
        for (int i = 0; i < 4; ++i) {
            const int r = rb + 4 * i;
            out[(row0 + r) * NX + c] = acc[i] + bb;
        }
    }
}

extern "C" void kernel_launch(void* const* d_in, const int* in_sizes, int n_in,
                              void* d_out, int out_size, void* d_ws, size_t ws_size,
                              hipStream_t stream) {
    const float* x0    = (const float*)d_in[0];
    const float* logdt = (const float*)d_in[1];
    const float* eW1  = (const float*)d_in[4];
    const float* eb1  = (const float*)d_in[5];
    const float* eg1  = (const float*)d_in[6];
    const float* ebe1 = (const float*)d_in[7];
    const float* eW2  = (const float*)d_in[8];
    const float* eb2  = (const float*)d_in[9];
    const float* eg2  = (const float*)d_in[10];
    const float* ebe2 = (const float*)d_in[11];
    const float* eW3  = (const float*)d_in[12];
    const float* eb3  = (const float*)d_in[13];
    const float* dW1  = (const float*)d_in[14];
    const float* db1  = (const float*)d_in[15];
    const float* dg1  = (const float*)d_in[16];
    const float* dbe1 = (const float*)d_in[17];
    const float* dW2  = (const float*)d_in[18];
    const float* db2  = (const float*)d_in[19];
    const float* dg2  = (const float*)d_in[20];
    const float* dbe2 = (const float*)d_in[21];
    const float* dW3  = (const float*)d_in[22];
    const float* db3  = (const float*)d_in[23];
    const float* Xi   = (const float*)d_in[24];
    float* out = (float*)d_out;

    if (ws_size >= WS_NEW_BYTES) {
        short* wsb = (short*)d_ws;
        float* zt = (float*)((char*)d_ws + ZT_OFF_BYTES);
        prep_weights<<<WS_ELEMS3 / 256, 256, 0, stream>>>(eW1, eW2, dW2, dW3, eW3, dW1, wsb);
        sindy_enc_kernel<<<B_TOTAL / BM, NTH, 0, stream>>>(
            x0, logdt, eb1, eg1, ebe1, eb2, eg2, ebe2, eb3, Xi, wsb, zt);
        sindy_dec_kernel<<<B_TOTAL / BM, NTH, 0, stream>>>(
            zt, db1, dg1, dbe1, db2, dg2, dbe2, db3, wsb, out);
    } else {
        sindy_fallback_kernel<<<B_TOTAL / FB_R, FB_NT, 0, stream>>>(
            x0, logdt, eW1, eb1, eg1, ebe1, eW2, eb2, eg2, ebe2, eW3, eb3,
            dW1, db1, dg1, dbe1, dW2, db2, dg2, dbe2, dW3, db3, Xi, out);
    }
}